// Round 9
// baseline (327.238 us; speedup 1.0000x reference)
//
#include <hip/hip_runtime.h>

// Problem constants
constexpr int BATCH = 8;
constexpr int NPT   = 8192;   // N points
constexpr int NSMP  = 2048;   // S sampled points
constexpr int D1C   = 128;    // skip feature channels
constexpr int D2C   = 256;    // sampled feature channels
constexpr int CIN   = 384;    // D1C + D2C
constexpr int C1    = 256;    // layer-1 out channels
constexpr int C2    = 128;    // layer-2 out channels
constexpr int BN_TOTAL = BATCH * NPT;  // 65536 rows

// Wave-GEMM tiling: one 64-lane wave per block, 128x64 tile, K-chunk 32.
constexpr int WM = 128, WN = 64, WK = 32;
constexpr int NRB = BN_TOTAL / WM;  // 512 row-blocks

typedef __bf16 bf16x8 __attribute__((ext_vector_type(8)));
typedef short  s16x8  __attribute__((ext_vector_type(8)));
typedef float  f32x4  __attribute__((ext_vector_type(4)));

__device__ __forceinline__ unsigned short f2bf(float x) {
  unsigned u = __builtin_bit_cast(unsigned, x);
  u += 0x7fffu + ((u >> 16) & 1u);   // round-to-nearest-even
  return (unsigned short)(u >> 16);
}
__device__ __forceinline__ float bf2f(unsigned short h) {
  return __builtin_bit_cast(float, (unsigned)h << 16);
}

// async global -> LDS, 16 B per lane; lds dest wave-uniform base + lane*16
__device__ __forceinline__ void gld_lds16(const void* g, void* l) {
  __builtin_amdgcn_global_load_lds(
      (const __attribute__((address_space(1))) void*)g,
      (__attribute__((address_space(3))) void*)l, 16, 0, 0);
}

// ---------------------------------------------------------------------------
// 32x32 tiled transpose (fp32)
// ---------------------------------------------------------------------------
__global__ void transpose_k(const float* __restrict__ in, float* __restrict__ out,
                            int rows, int cols, long inBatch, long outBatch) {
  __shared__ float tile[32][33];
  const float* inb = in + (size_t)blockIdx.z * inBatch;
  float* outb = out + (size_t)blockIdx.z * outBatch;
  int c0 = blockIdx.x * 32;
  int r0 = blockIdx.y * 32;
  int tx = threadIdx.x, ty = threadIdx.y;
#pragma unroll
  for (int i = 0; i < 32; i += 8) {
    int r = r0 + ty + i;
    tile[ty + i][tx] = inb[(size_t)r * cols + c0 + tx];
  }
  __syncthreads();
#pragma unroll
  for (int i = 0; i < 32; i += 8) {
    int c = c0 + ty + i;
    outb[(size_t)c * rows + r0 + tx] = tile[tx][ty + i];
  }
}

// ---------------------------------------------------------------------------
// skip [B, D1C, NPT] fp32 -> featB[b*NPT+n][d] bf16 (columns 0..127)
// ---------------------------------------------------------------------------
__global__ void skip_to_featB(const float* __restrict__ skip,
                              unsigned short* __restrict__ featB) {
  __shared__ float tile[32][33];
  int b = blockIdx.z;
  int n0 = blockIdx.x * 32;
  int d0 = blockIdx.y * 32;
  int tx = threadIdx.x, ty = threadIdx.y;
#pragma unroll
  for (int i = 0; i < 32; i += 8) {
    tile[ty + i][tx] = skip[((size_t)b * D1C + d0 + ty + i) * NPT + n0 + tx];
  }
  __syncthreads();
#pragma unroll
  for (int i = 0; i < 32; i += 8) {
    int n = n0 + ty + i;
    featB[((size_t)b * NPT + n) * CIN + d0 + tx] = f2bf(tile[tx][ty + i]);
  }
}

// ---------------------------------------------------------------------------
// Weight prep: W fp32 -> bf16
// ---------------------------------------------------------------------------
__global__ void wprep(const float* __restrict__ W, unsigned short* __restrict__ Wh,
                      int total) {
  int i = blockIdx.x * 256 + threadIdx.x;
  if (i >= total) return;
  Wh[i] = f2bf(W[i]);
}

// ---------------------------------------------------------------------------
// Pack spos: original interleaved sposI [B,NSMP,3] (for exact fp64 paths)
// and transformed qs4 [B,NSMP,4] = (-2x, -2y, -2z, |q|^2) for the scan.
// ---------------------------------------------------------------------------
__global__ void pack_spos(const float* __restrict__ spos, float* __restrict__ sposI,
                          float4* __restrict__ qs4) {
  int g = blockIdx.x * 256 + threadIdx.x;  // B*NSMP = 16384
  int b = g >> 11, s = g & (NSMP - 1);
  const float* sp = spos + (size_t)b * 3 * NSMP;
  float x = sp[s], y = sp[NSMP + s], z = sp[2 * NSMP + s];
  sposI[(size_t)g * 3 + 0] = x;
  sposI[(size_t)g * 3 + 1] = y;
  sposI[(size_t)g * 3 + 2] = z;
  qs4[g] = make_float4(-2.f * x, -2.f * y, -2.f * z,
                       fmaf(x, x, fmaf(y, y, z * z)));
}

// ---------------------------------------------------------------------------
// kNN scan, ~8 VALU ops/pair, sample constants via wave-uniform (scalar-pipe)
// global loads — no LDS staging, no per-sample ds_read return-bus cost:
//   d' = fma(px,-2qx, fma(py,-2qy, fma(pz,-2qz, |q|^2)))  (3 fma; shifted by
//        -|p|^2 vs true distance — ordering invariant)
//   ki = (bits(d') & ~0x7FF) | s                           (1 v_and_or_b32)
//   sorted top-4 insert via min + 3x v_med3_f32            (4 ops)
// Keys may be negative: float-valued min/med3 sorting still orders correctly;
// within-bucket tie-break direction flips for negative keys, which is safe:
// within-top-3 order doesn't affect output, and a 2/3-boundary bucket
// collision gives gap==0 -> flagged -> exact fp64 fallback.
// ---------------------------------------------------------------------------
constexpr int SEG = NSMP / 4;  // 512

__device__ __forceinline__ void ins_med3(float kf, float& k0, float& k1,
                                         float& k2, float& k3) {
  float o0 = k0, o1 = k1, o2 = k2;
  k0 = fminf(kf, o0);
  k1 = __builtin_amdgcn_fmed3f(kf, o0, o1);
  k2 = __builtin_amdgcn_fmed3f(kf, o1, o2);
  k3 = __builtin_amdgcn_fmed3f(kf, o2, k3);
}

__global__ __launch_bounds__(256) void knn_kernel(
    const float* __restrict__ pos,    // [B,3,NPT]
    const float4* __restrict__ qs4g,  // [B,NSMP] transformed
    const float* __restrict__ sposI,  // [B,NSMP,3] original (fp64 weights)
    int* __restrict__ idx_out,        // [BN_TOTAL,3]
    float* __restrict__ wgt_out,      // [BN_TOTAL,3]
    int* __restrict__ flag_list,
    int* __restrict__ flag_count) {
  __shared__ float mk[4][4][64];   // per-wave sorted top-4 keys (4 KB)

  int tid = threadIdx.x;
  int wave = tid >> 6, lane = tid & 63;
  int blk = blockIdx.x;
  int b = blk >> 7;
  int n = ((blk & 127) << 6) + lane;

  const float* pb = pos + (size_t)b * 3 * NPT;
  float px = pb[n], py = pb[NPT + n], pz = pb[2 * NPT + n];
  float pp = fmaf(px, px, fmaf(py, py, pz * pz));

  const float INF = __builtin_inff();
  float k0 = INF, k1 = INF, k2 = INF, k3 = INF;

  // block-uniform base; loop-uniform index -> compiler emits s_load (SMEM)
  const float4* __restrict__ qv = qs4g + (size_t)b * NSMP;
  int s0 = wave * SEG;

#define KNN_STEP(Q, SS)                                                   \
  {                                                                       \
    float d = fmaf(px, (Q).x, fmaf(py, (Q).y, fmaf(pz, (Q).z, (Q).w)));   \
    unsigned ki = (__builtin_bit_cast(unsigned, d) & 0xFFFFF800u) |       \
                  (unsigned)(SS);                                         \
    ins_med3(__builtin_bit_cast(float, ki), k0, k1, k2, k3);              \
  }

  for (int t = 0; t < SEG; t += 4) {
    int s = s0 + t;
    float4 qa = qv[s], qb = qv[s + 1], qc = qv[s + 2], qd = qv[s + 3];
    KNN_STEP(qa, s + 0)
    KNN_STEP(qb, s + 1)
    KNN_STEP(qc, s + 2)
    KNN_STEP(qd, s + 3)
  }
#undef KNN_STEP

  mk[wave][0][lane] = k0; mk[wave][1][lane] = k1;
  mk[wave][2][lane] = k2; mk[wave][3][lane] = k3;
  __syncthreads();

  if (tid < 64) {
    float K0 = INF, K1 = INF, K2 = INF, K3 = INF;
#pragma unroll
    for (int w = 0; w < 4; w++)
#pragma unroll
      for (int sl = 0; sl < 4; sl++)
        ins_med3(mk[w][sl][tid], K0, K1, K2, K3);

    int p = blk * 64 + tid;
    int I0 = (int)(__builtin_bit_cast(unsigned, K0) & 0x7FFu);
    int I1 = (int)(__builtin_bit_cast(unsigned, K1) & 0x7FFu);
    int I2 = (int)(__builtin_bit_cast(unsigned, K2) & 0x7FFu);
    float d2m = __builtin_bit_cast(float, __builtin_bit_cast(unsigned, K2) & 0xFFFFF800u);
    float d3m = __builtin_bit_cast(float, __builtin_bit_cast(unsigned, K3) & 0xFFFFF800u);
    // keys are shifted by -pp; rescale certification with true magnitude
    bool flag = (d3m - d2m) < 2e-3f * fmaxf(d3m + pp, 0.f) + 1e-5f;
    if (flag) {
      int slot = atomicAdd(flag_count, 1);
      flag_list[slot] = p;
    }
    // exact fp64 weights from chosen indices (original coords, diff form)
    const float* q = sposI + (size_t)b * 3 * NSMP;
    double pxd = (double)px, pyd = (double)py, pzd = (double)pz;
    double dd[3]; int II[3] = {I0, I1, I2};
#pragma unroll
    for (int k = 0; k < 3; k++) {
      double dx = pxd - (double)q[3 * II[k]];
      double dy = pyd - (double)q[3 * II[k] + 1];
      double dz = pzd - (double)q[3 * II[k] + 2];
      dd[k] = dx * dx + dy * dy + dz * dz;
    }
    double w0 = 1.0 / (dd[0] + 1e-8);
    double w1 = 1.0 / (dd[1] + 1e-8);
    double w2 = 1.0 / (dd[2] + 1e-8);
    double inv = 1.0 / (w0 + w1 + w2);
    size_t o = (size_t)p * 3;
    idx_out[o + 0] = I0; idx_out[o + 1] = I1; idx_out[o + 2] = I2;
    wgt_out[o + 0] = (float)(w0 * inv);
    wgt_out[o + 1] = (float)(w1 * inv);
    wgt_out[o + 2] = (float)(w2 * inv);
  }
}

// ---------------------------------------------------------------------------
// Exact fp64 fallback, wave-parallel (original coords, difference form).
// ---------------------------------------------------------------------------
__device__ __forceinline__ bool dless(double d, int i, double D, int I) {
  return d < D || (d == D && i < I);
}
__device__ __forceinline__ void dins3(double d, int i,
                                      double& b0, double& b1, double& b2,
                                      int& i0, int& i1, int& i2) {
  if (dless(d, i, b2, i2)) {
    if (dless(d, i, b1, i1)) {
      b2 = b1; i2 = i1;
      if (dless(d, i, b0, i0)) { b1 = b0; i1 = i0; b0 = d; i0 = i; }
      else                     { b1 = d; i1 = i; }
    } else { b2 = d; i2 = i; }
  }
}

__global__ __launch_bounds__(256) void knn_fallback(
    const float* __restrict__ pos, const float* __restrict__ sposI,
    const int* __restrict__ flag_list, const int* __restrict__ flag_count,
    int* __restrict__ idx_out, float* __restrict__ wgt_out) {
  int wave = threadIdx.x >> 6, lane = threadIdx.x & 63;
  int gw = blockIdx.x * 4 + wave;
  int cnt = *flag_count;
  for (int t = gw; t < cnt; t += 1024) {
    int p = flag_list[t];
    int b = p >> 13, n = p & (NPT - 1);
    const float* pb = pos + (size_t)b * 3 * NPT;
    double px = (double)pb[n], py = (double)pb[NPT + n], pz = (double)pb[2 * NPT + n];
    const float* q = sposI + (size_t)b * 3 * NSMP;
    double b0 = 1e300, b1 = 1e300, b2 = 1e300;
    int i0 = 0x7FFFFFFF, i1 = 0x7FFFFFFF, i2 = 0x7FFFFFFF;
    for (int s = lane; s < NSMP; s += 64) {
      double dx = px - (double)q[3 * s];
      double dy = py - (double)q[3 * s + 1];
      double dz = pz - (double)q[3 * s + 2];
      double d = dx * dx + dy * dy + dz * dz;
      dins3(d, s, b0, b1, b2, i0, i1, i2);
    }
#pragma unroll
    for (int m = 1; m < 64; m <<= 1) {
      double o0 = __shfl_xor(b0, m, 64), o1 = __shfl_xor(b1, m, 64), o2 = __shfl_xor(b2, m, 64);
      int    j0 = __shfl_xor(i0, m, 64), j1 = __shfl_xor(i1, m, 64), j2 = __shfl_xor(i2, m, 64);
      dins3(o0, j0, b0, b1, b2, i0, i1, i2);
      dins3(o1, j1, b0, b1, b2, i0, i1, i2);
      dins3(o2, j2, b0, b1, b2, i0, i1, i2);
    }
    if (lane == 0) {
      double w0 = 1.0 / (b0 + 1e-8);
      double w1 = 1.0 / (b1 + 1e-8);
      double w2 = 1.0 / (b2 + 1e-8);
      double inv = 1.0 / (w0 + w1 + w2);
      size_t o = (size_t)p * 3;
      idx_out[o + 0] = i0; idx_out[o + 1] = i1; idx_out[o + 2] = i2;
      wgt_out[o + 0] = (float)(w0 * inv);
      wgt_out[o + 1] = (float)(w1 * inv);
      wgt_out[o + 2] = (float)(w2 * inv);
    }
  }
}

// ---------------------------------------------------------------------------
// Interp gather -> featB columns 128..383 (bf16)
// ---------------------------------------------------------------------------
__global__ __launch_bounds__(256) void interp_kernel(
    const float* __restrict__ sfeatT,  // [B, NSMP, D2C]
    const int* __restrict__ idx,
    const float* __restrict__ wgt,
    unsigned short* __restrict__ featB) {
  int p = blockIdx.x;
  int c = threadIdx.x;
  int b = p >> 13;
  size_t o = (size_t)p * 3;
  int i0 = idx[o], i1 = idx[o + 1], i2 = idx[o + 2];
  float w0 = wgt[o], w1 = wgt[o + 1], w2 = wgt[o + 2];
  const float* base = sfeatT + (size_t)b * NSMP * D2C;
  float v = w0 * base[(size_t)i0 * D2C + c]
          + w1 * base[(size_t)i1 * D2C + c]
          + w2 * base[(size_t)i2 * D2C + c];
  featB[(size_t)p * CIN + D1C + c] = f2bf(v);
}

// ---------------------------------------------------------------------------
// GEMM1, single-wave blocks: Y1 = featB @ W1^T + b1, 128x64 tile/wave.
// Partial (sum,sumsq) per [col][rowblock]; no atomics.
// grid (NRB, C1/WN) = (512, 4), block 64.
// ---------------------------------------------------------------------------
__global__ __launch_bounds__(64) void gemm1_wave(
    const unsigned short* __restrict__ featB,  // [BN_TOTAL][CIN] bf16
    const unsigned short* __restrict__ W1h,    // [C1][CIN] bf16
    const float* __restrict__ bias,
    unsigned short* __restrict__ Y1,           // [BN_TOTAL][C1] bf16
    float* __restrict__ part_s,                // [C1][NRB]
    float* __restrict__ part_q) {
  __shared__ __align__(16) unsigned short As[WM * WK];  // 8 KB
  __shared__ __align__(16) unsigned short Bs[WN * WK];  // 4 KB
  int lane = threadIdx.x;
  int m16 = lane & 15, quad = lane >> 4;
  int rb = blockIdx.x, cb = blockIdx.y;
  int row0 = rb * WM, col0 = cb * WN;
  int row16 = lane >> 2, col8 = (lane & 3) * 8;

  f32x4 acc[8][4];
#pragma unroll
  for (int j = 0; j < 4; j++) {
    float bj = bias[col0 + j * 16 + m16];
#pragma unroll
    for (int i = 0; i < 8; i++) acc[i][j] = f32x4{bj, bj, bj, bj};
  }

  for (int k0 = 0; k0 < CIN; k0 += WK) {
#pragma unroll
    for (int c = 0; c < 8; c++)
      gld_lds16(&featB[(size_t)(row0 + c * 16 + row16) * CIN + k0 + col8],
                &As[c * 16 * WK]);
#pragma unroll
    for (int c = 0; c < 4; c++)
      gld_lds16(&W1h[(size_t)(col0 + c * 16 + row16) * CIN + k0 + col8],
                &Bs[c * 16 * WK]);
    __syncthreads();  // 1-wave block: local waitcnt, no cross-wave drain

    bf16x8 a[8], bf[4];
#pragma unroll
    for (int i = 0; i < 8; i++)
      a[i] = __builtin_bit_cast(bf16x8, *(const s16x8*)&As[(i * 16 + m16) * WK + quad * 8]);
#pragma unroll
    for (int j = 0; j < 4; j++)
      bf[j] = __builtin_bit_cast(bf16x8, *(const s16x8*)&Bs[(j * 16 + m16) * WK + quad * 8]);
#pragma unroll
    for (int i = 0; i < 8; i++)
#pragma unroll
      for (int j = 0; j < 4; j++)
        acc[i][j] = __builtin_amdgcn_mfma_f32_16x16x32_bf16(a[i], bf[j], acc[i][j], 0, 0, 0);
    __syncthreads();
  }

#pragma unroll
  for (int j = 0; j < 4; j++) {
    int col = col0 + j * 16 + m16;
    float s = 0.f, q = 0.f;
#pragma unroll
    for (int i = 0; i < 8; i++)
#pragma unroll
      for (int r = 0; r < 4; r++) {
        float v = acc[i][j][r];
        Y1[(size_t)(row0 + i * 16 + quad * 4 + r) * C1 + col] = f2bf(v);
        s += v; q = fmaf(v, v, q);
      }
    s += __shfl_xor(s, 16, 64); s += __shfl_xor(s, 32, 64);
    q += __shfl_xor(q, 16, 64); q += __shfl_xor(q, 32, 64);
    if (quad == 0) {
      part_s[(size_t)col * NRB + rb] = s;
      part_q[(size_t)col * NRB + rb] = q;
    }
  }
}

// ---------------------------------------------------------------------------
// GEMM2, single-wave blocks: X2 = relu(bn1(Y1)) fused in A staging (VALU),
// B via global_load_lds. 128x64 tile/wave. grid (NRB, C2/WN) = (512, 2).
// ---------------------------------------------------------------------------
__global__ __launch_bounds__(64) void gemm2_wave(
    const unsigned short* __restrict__ Y1,   // [BN_TOTAL][C1] bf16
    const float* __restrict__ scale1, const float* __restrict__ shift1,
    const unsigned short* __restrict__ W2h,  // [C2][C1] bf16
    const float* __restrict__ bias,
    unsigned short* __restrict__ Y2,         // [BN_TOTAL][C2] bf16
    float* __restrict__ part_s,              // [C2][NRB]
    float* __restrict__ part_q) {
  __shared__ __align__(16) unsigned short As[WM * WK];
  __shared__ __align__(16) unsigned short Bs[WN * WK];
  __shared__ float scs[C1], shs[C1];
  int lane = threadIdx.x;
  int m16 = lane & 15, quad = lane >> 4;
  int rb = blockIdx.x, cb = blockIdx.y;
  int row0 = rb * WM, col0 = cb * WN;
  int row16 = lane >> 2, col8 = (lane & 3) * 8;

  for (int t = lane; t < C1; t += 64) { scs[t] = scale1[t]; shs[t] = shift1[t]; }

  f32x4 acc[8][4];
#pragma unroll
  for (int j = 0; j < 4; j++) {
    float bj = bias[col0 + j * 16 + m16];
#pragma unroll
    for (int i = 0; i < 8; i++) acc[i][j] = f32x4{bj, bj, bj, bj};
  }
  __syncthreads();  // scs/shs visible (single wave: cheap)

  for (int k0 = 0; k0 < C1; k0 += WK) {
#pragma unroll
    for (int c = 0; c < 4; c++)
      gld_lds16(&W2h[(size_t)(col0 + c * 16 + row16) * C1 + k0 + col8],
                &Bs[c * 16 * WK]);
    // A tile: load Y1, apply BN1+ReLU, write LDS
#pragma unroll
    for (int c = 0; c < 8; c++) {
      int row = c * 16 + row16;
      s16x8 v = *(const s16x8*)&Y1[(size_t)(row0 + row) * C1 + k0 + col8];
      unsigned short ov[8];
#pragma unroll
      for (int e = 0; e < 8; e++) {
        float x = bf2f((unsigned short)v[e]);
        float y = fmaxf(fmaf(x, scs[k0 + col8 + e], shs[k0 + col8 + e]), 0.f);
        ov[e] = f2bf(y);
      }
      *(s16x8*)&As[row * WK + col8] = *(const s16x8*)ov;
    }
    __syncthreads();

    bf16x8 a[8], bf[4];
#pragma unroll
    for (int i = 0; i < 8; i++)
      a[i] = __builtin_bit_cast(bf16x8, *(const s16x8*)&As[(i * 16 + m16) * WK + quad * 8]);
#pragma unroll
    for (int j = 0; j < 4; j++)
      bf[j] = __builtin_bit_cast(bf16x8, *(const s16x8*)&Bs[(j * 16 + m16) * WK + quad * 8]);
#pragma unroll
    for (int i = 0; i < 8; i++)
#pragma unroll
      for (int j = 0; j < 4; j++)
        acc[i][j] = __builtin_amdgcn_mfma_f32_16x16x32_bf16(a[i], bf[j], acc[i][j], 0, 0, 0);
    __syncthreads();
  }

#pragma unroll
  for (int j = 0; j < 4; j++) {
    int col = col0 + j * 16 + m16;
    float s = 0.f, q = 0.f;
#pragma unroll
    for (int i = 0; i < 8; i++)
#pragma unroll
      for (int r = 0; r < 4; r++) {
        float v = acc[i][j][r];
        Y2[(size_t)(row0 + i * 16 + quad * 4 + r) * C2 + col] = f2bf(v);
        s += v; q = fmaf(v, v, q);
      }
    s += __shfl_xor(s, 16, 64); s += __shfl_xor(s, 32, 64);
    q += __shfl_xor(q, 16, 64); q += __shfl_xor(q, 32, 64);
    if (quad == 0) {
      part_s[(size_t)col * NRB + rb] = s;
      part_q[(size_t)col * NRB + rb] = q;
    }
  }
}

// ---------------------------------------------------------------------------
// Reduce partials [C][NRB] + compute BN scale/shift. grid = C, block = 256.
// ---------------------------------------------------------------------------
__global__ __launch_bounds__(256) void bn_reduce_coef(
    const float* __restrict__ part_s, const float* __restrict__ part_q, int nrb,
    const float* __restrict__ g, const float* __restrict__ beta,
    float* __restrict__ scale, float* __restrict__ shift) {
  int ch = blockIdx.x;
  int tid = threadIdx.x;
  float s = 0.f, q = 0.f;
  for (int t = tid; t < nrb; t += 256) {
    s += part_s[(size_t)ch * nrb + t];
    q += part_q[(size_t)ch * nrb + t];
  }
#pragma unroll
  for (int m = 1; m < 64; m <<= 1) {
    s += __shfl_xor(s, m, 64);
    q += __shfl_xor(q, m, 64);
  }
  __shared__ float ls[4], lq[4];
  int wave = tid >> 6;
  if ((tid & 63) == 0) { ls[wave] = s; lq[wave] = q; }
  __syncthreads();
  if (tid == 0) {
    s = ls[0] + ls[1] + ls[2] + ls[3];
    q = lq[0] + lq[1] + lq[2] + lq[3];
    const float invBN = 1.0f / (float)BN_TOTAL;
    float mean = s * invBN;
    float var = q * invBN - mean * mean;
    float sc = g[ch] / sqrtf(var + 1e-5f);
    scale[ch] = sc;
    shift[ch] = beta[ch] - mean * sc;
  }
}

// ---------------------------------------------------------------------------
// Final: out[b][c][n] = relu(bn2(Y2)) transposed, fp32 out.
// ---------------------------------------------------------------------------
__global__ void final_kernel(const unsigned short* __restrict__ Y2,
                             const float* __restrict__ scale, const float* __restrict__ shift,
                             float* __restrict__ out) {
  __shared__ float tile[32][33];
  int b = blockIdx.z;
  int n0 = blockIdx.x * 32;
  int c0 = blockIdx.y * 32;
  int tx = threadIdx.x, ty = threadIdx.y;
  float sc = scale[c0 + tx];
  float sh = shift[c0 + tx];
#pragma unroll
  for (int i = 0; i < 32; i += 8) {
    int n = n0 + ty + i;
    float v = bf2f(Y2[((size_t)b * NPT + n) * C2 + c0 + tx]);
    tile[ty + i][tx] = fmaxf(fmaf(v, sc, sh), 0.f);
  }
  __syncthreads();
#pragma unroll
  for (int i = 0; i < 32; i += 8) {
    int c = c0 + ty + i;
    out[((size_t)b * C2 + c) * NPT + n0 + tx] = tile[tx][ty + i];
  }
}

// ---------------------------------------------------------------------------
extern "C" void kernel_launch(void* const* d_in, const int* in_sizes, int n_in,
                              void* d_out, int out_size, void* d_ws, size_t ws_size,
                              hipStream_t stream) {
  (void)in_sizes; (void)n_in; (void)out_size; (void)ws_size;
  const float* pos   = (const float*)d_in[0];
  const float* spos  = (const float*)d_in[1];
  const float* skip  = (const float*)d_in[2];
  const float* sfeat = (const float*)d_in[3];
  const float* W1    = (const float*)d_in[4];
  const float* b1    = (const float*)d_in[5];
  const float* g1    = (const float*)d_in[6];
  const float* beta1 = (const float*)d_in[7];
  const float* W2    = (const float*)d_in[8];
  const float* b2    = (const float*)d_in[9];
  const float* g2    = (const float*)d_in[10];
  const float* beta2 = (const float*)d_in[11];
  float* out = (float*)d_out;

  float* ws = (float*)d_ws;
  size_t off = 0;
  float* sfeatT  = ws + off; off += (size_t)BATCH * NSMP * D2C;
  unsigned short* featB = (unsigned short*)(ws + off); off += (size_t)BN_TOTAL * CIN / 2;
  unsigned short* Y1    = (unsigned short*)(ws + off); off += (size_t)BN_TOTAL * C1 / 2;
  unsigned short* Y2    = (unsigned short*)(ws + off); off += (size_t)BN_TOTAL * C2 / 2;
  unsigned short* W1h   = (unsigned short*)(ws + off); off += (size_t)C1 * CIN / 2;
  unsigned short* W2h   = (unsigned short*)(ws + off); off += (size_t)C2 * C1 / 2;
  int*   knn_idx = (int*)(ws + off); off += (size_t)BN_TOTAL * 3;
  float* knn_w   = ws + off; off += (size_t)BN_TOTAL * 3;
  float* sposI   = ws + off; off += (size_t)BATCH * NSMP * 3;
  float4* qs4    = (float4*)(ws + off); off += (size_t)BATCH * NSMP * 4;
  int* flag_list = (int*)(ws + off); off += (size_t)BN_TOTAL;
  float* part1_s = ws + off; off += (size_t)C1 * NRB;
  float* part1_q = ws + off; off += (size_t)C1 * NRB;
  float* part2_s = ws + off; off += (size_t)C2 * NRB;
  float* part2_q = ws + off; off += (size_t)C2 * NRB;
  float* stats   = ws + off; off += 2048;
  int*   flag_count = (int*)stats;
  float* scale1 = stats + 256, *shift1 = stats + 512;
  float* scale2 = stats + 768, *shift2 = stats + 1024;

  hipMemsetAsync(flag_count, 0, sizeof(int), stream);

  dim3 tb(32, 8);
  transpose_k<<<dim3(NSMP / 32, D2C / 32, BATCH), tb, 0, stream>>>(
      sfeat, sfeatT, D2C, NSMP, (long)D2C * NSMP, (long)NSMP * D2C);
  wprep<<<(C1 * CIN + 255) / 256, 256, 0, stream>>>(W1, W1h, C1 * CIN);
  wprep<<<(C2 * C1 + 255) / 256, 256, 0, stream>>>(W2, W2h, C2 * C1);
  skip_to_featB<<<dim3(NPT / 32, D1C / 32, BATCH), tb, 0, stream>>>(skip, featB);

  pack_spos<<<BATCH * NSMP / 256, 256, 0, stream>>>(spos, sposI, qs4);
  knn_kernel<<<BN_TOTAL / 64, 256, 0, stream>>>(pos, qs4, sposI, knn_idx, knn_w,
                                                flag_list, flag_count);
  knn_fallback<<<256, 256, 0, stream>>>(pos, sposI, flag_list, flag_count,
                                        knn_idx, knn_w);
  interp_kernel<<<BN_TOTAL, 256, 0, stream>>>(sfeatT, knn_idx, knn_w, featB);

  gemm1_wave<<<dim3(NRB, C1 / WN), 64, 0, stream>>>(
      featB, W1h, b1, Y1, part1_s, part1_q);
  bn_reduce_coef<<<C1, 256, 0, stream>>>(part1_s, part1_q, NRB, g1, beta1, scale1, shift1);

  gemm2_wave<<<dim3(NRB, C2 / WN), 64, 0, stream>>>(
      Y1, scale1, shift1, W2h, b2, Y2, part2_s, part2_q);
  bn_reduce_coef<<<C2, 256, 0, stream>>>(part2_s, part2_q, NRB, g2, beta2, scale2, shift2);

  final_kernel<<<dim3(NPT / 32, C2 / 32, BATCH), tb, 0, stream>>>(Y2, scale2, shift2, out);
}

// Round 10
// 313.699 us; speedup vs baseline: 1.0432x; 1.0432x over previous
//
#include <hip/hip_runtime.h>

// Problem constants
constexpr int BATCH = 8;
constexpr int NPT   = 8192;   // N points
constexpr int NSMP  = 2048;   // S sampled points
constexpr int D1C   = 128;    // skip feature channels
constexpr int D2C   = 256;    // sampled feature channels
constexpr int CIN   = 384;    // D1C + D2C
constexpr int C1    = 256;    // layer-1 out channels
constexpr int C2    = 128;    // layer-2 out channels
constexpr int BN_TOTAL = BATCH * NPT;  // 65536 rows

// Wave-GEMM tiling: one 64-lane wave per block, 128x64 tile, K-chunk 32.
constexpr int WM = 128, WN = 64, WK = 32;
constexpr int NRB = BN_TOTAL / WM;  // 512 row-blocks

typedef __bf16 bf16x8 __attribute__((ext_vector_type(8)));
typedef short  s16x8  __attribute__((ext_vector_type(8)));
typedef float  f32x4  __attribute__((ext_vector_type(4)));

__device__ __forceinline__ unsigned short f2bf(float x) {
  unsigned u = __builtin_bit_cast(unsigned, x);
  u += 0x7fffu + ((u >> 16) & 1u);   // round-to-nearest-even
  return (unsigned short)(u >> 16);
}
__device__ __forceinline__ float bf2f(unsigned short h) {
  return __builtin_bit_cast(float, (unsigned)h << 16);
}

// async global -> LDS, 16 B per lane; lds dest wave-uniform base + lane*16
__device__ __forceinline__ void gld_lds16(const void* g, void* l) {
  __builtin_amdgcn_global_load_lds(
      (const __attribute__((address_space(1))) void*)g,
      (__attribute__((address_space(3))) void*)l, 16, 0, 0);
}

// ---------------------------------------------------------------------------
// 32x32 tiled transpose (fp32)
// ---------------------------------------------------------------------------
__global__ void transpose_k(const float* __restrict__ in, float* __restrict__ out,
                            int rows, int cols, long inBatch, long outBatch) {
  __shared__ float tile[32][33];
  const float* inb = in + (size_t)blockIdx.z * inBatch;
  float* outb = out + (size_t)blockIdx.z * outBatch;
  int c0 = blockIdx.x * 32;
  int r0 = blockIdx.y * 32;
  int tx = threadIdx.x, ty = threadIdx.y;
#pragma unroll
  for (int i = 0; i < 32; i += 8) {
    int r = r0 + ty + i;
    tile[ty + i][tx] = inb[(size_t)r * cols + c0 + tx];
  }
  __syncthreads();
#pragma unroll
  for (int i = 0; i < 32; i += 8) {
    int c = c0 + ty + i;
    outb[(size_t)c * rows + r0 + tx] = tile[tx][ty + i];
  }
}

// ---------------------------------------------------------------------------
// skip [B, D1C, NPT] fp32 -> featB[b*NPT+n][d] bf16 (columns 0..127)
// ---------------------------------------------------------------------------
__global__ void skip_to_featB(const float* __restrict__ skip,
                              unsigned short* __restrict__ featB) {
  __shared__ float tile[32][33];
  int b = blockIdx.z;
  int n0 = blockIdx.x * 32;
  int d0 = blockIdx.y * 32;
  int tx = threadIdx.x, ty = threadIdx.y;
#pragma unroll
  for (int i = 0; i < 32; i += 8) {
    tile[ty + i][tx] = skip[((size_t)b * D1C + d0 + ty + i) * NPT + n0 + tx];
  }
  __syncthreads();
#pragma unroll
  for (int i = 0; i < 32; i += 8) {
    int n = n0 + ty + i;
    featB[((size_t)b * NPT + n) * CIN + d0 + tx] = f2bf(tile[tx][ty + i]);
  }
}

// ---------------------------------------------------------------------------
// Weight prep: W fp32 -> bf16
// ---------------------------------------------------------------------------
__global__ void wprep(const float* __restrict__ W, unsigned short* __restrict__ Wh,
                      int total) {
  int i = blockIdx.x * 256 + threadIdx.x;
  if (i >= total) return;
  Wh[i] = f2bf(W[i]);
}

// ---------------------------------------------------------------------------
// Pack spos: original interleaved sposI [B,NSMP,3] (for exact fp64 paths)
// and transformed qs4 [B,NSMP,4] = (-2x, -2y, -2z, |q|^2) for the scan.
// ---------------------------------------------------------------------------
__global__ void pack_spos(const float* __restrict__ spos, float* __restrict__ sposI,
                          float4* __restrict__ qs4) {
  int g = blockIdx.x * 256 + threadIdx.x;  // B*NSMP = 16384
  int b = g >> 11, s = g & (NSMP - 1);
  const float* sp = spos + (size_t)b * 3 * NSMP;
  float x = sp[s], y = sp[NSMP + s], z = sp[2 * NSMP + s];
  sposI[(size_t)g * 3 + 0] = x;
  sposI[(size_t)g * 3 + 1] = y;
  sposI[(size_t)g * 3 + 2] = z;
  qs4[g] = make_float4(-2.f * x, -2.f * y, -2.f * z,
                       fmaf(x, x, fmaf(y, y, z * z)));
}

// ---------------------------------------------------------------------------
// kNN: LDS-staged samples (round-8 structure), 4 POINTS PER LANE to amortize
// the broadcast ds_read_b128 return-bus cost (the measured 46us bottleneck):
// per sample read, a wave does 4x(3 fma + 1 and_or + 4 med3-sort) = 32 VALU.
// Block 256 thr = 4 waves covers 256 points; each wave scans a 512-sample
// segment. Shifted distance d' = d - |p|^2 (ordering-invariant); packed keys
// (idx in low 11 bits); certification rescaled by +pp -> fp64 fallback.
// ---------------------------------------------------------------------------
constexpr int SEG = NSMP / 4;  // 512
constexpr int PPL = 4;         // points per lane

__device__ __forceinline__ void ins_med3(float kf, float& k0, float& k1,
                                         float& k2, float& k3) {
  float o0 = k0, o1 = k1, o2 = k2;
  k0 = fminf(kf, o0);
  k1 = __builtin_amdgcn_fmed3f(kf, o0, o1);
  k2 = __builtin_amdgcn_fmed3f(kf, o1, o2);
  k3 = __builtin_amdgcn_fmed3f(kf, o2, k3);
}

__global__ __launch_bounds__(256) void knn_kernel(
    const float* __restrict__ pos,    // [B,3,NPT]
    const float4* __restrict__ qs4g,  // [B,NSMP] transformed
    const float* __restrict__ sposI,  // [B,NSMP,3] original (fp64 weights)
    int* __restrict__ idx_out,        // [BN_TOTAL,3]
    float* __restrict__ wgt_out,      // [BN_TOTAL,3]
    int* __restrict__ flag_list,
    int* __restrict__ flag_count) {
  __shared__ float4 qs[NSMP];            // 32 KB
  __shared__ float mk[4][PPL][4][64];    // wave, pt, slot, lane (16 KB)

  int tid = threadIdx.x;
  int wave = tid >> 6, lane = tid & 63;
  int blk = blockIdx.x;            // 256 blocks total, 32 per batch
  int b = blk >> 5;
  int nbase = ((blk & 31) << 8) + lane;  // point n for p-slot 0

  const float4* src = qs4g + (size_t)b * NSMP;
  for (int t = tid; t < NSMP; t += 256) qs[t] = src[t];

  const float* pb = pos + (size_t)b * 3 * NPT;
  float px[PPL], py[PPL], pz[PPL];
#pragma unroll
  for (int p = 0; p < PPL; p++) {
    int n = nbase + 64 * p;
    px[p] = pb[n]; py[p] = pb[NPT + n]; pz[p] = pb[2 * NPT + n];
  }
  __syncthreads();

  const float INF = __builtin_inff();
  float k0[PPL], k1[PPL], k2[PPL], k3[PPL];
#pragma unroll
  for (int p = 0; p < PPL; p++) { k0[p] = INF; k1[p] = INF; k2[p] = INF; k3[p] = INF; }

  int s0 = wave * SEG;
  for (int t = 0; t < SEG; t += 4) {
    int s = s0 + t;
    float4 qq[4] = {qs[s], qs[s + 1], qs[s + 2], qs[s + 3]};
#pragma unroll
    for (int u = 0; u < 4; u++) {
      float4 q = qq[u];
      unsigned si = (unsigned)(s + u);
#pragma unroll
      for (int p = 0; p < PPL; p++) {
        float d = fmaf(px[p], q.x, fmaf(py[p], q.y, fmaf(pz[p], q.z, q.w)));
        unsigned ki = (__builtin_bit_cast(unsigned, d) & 0xFFFFF800u) | si;
        ins_med3(__builtin_bit_cast(float, ki), k0[p], k1[p], k2[p], k3[p]);
      }
    }
  }

#pragma unroll
  for (int p = 0; p < PPL; p++) {
    mk[wave][p][0][lane] = k0[p]; mk[wave][p][1][lane] = k1[p];
    mk[wave][p][2][lane] = k2[p]; mk[wave][p][3][lane] = k3[p];
  }
  __syncthreads();

  // merge: thread tid owns point p-slot (tid>>6), lane (tid&63) == its own
  // scan-phase point px[tid>>6] etc.
  {
    int myp = tid >> 6, myl = tid & 63;
    float K0 = INF, K1 = INF, K2 = INF, K3 = INF;
#pragma unroll
    for (int w = 0; w < 4; w++)
#pragma unroll
      for (int sl = 0; sl < 4; sl++)
        ins_med3(mk[w][myp][sl][myl], K0, K1, K2, K3);

    float fx = px[myp], fy = py[myp], fz = pz[myp];
    float pp = fmaf(fx, fx, fmaf(fy, fy, fz * fz));

    int p = blk * 256 + tid;   // global point id == b*NPT + (blk&31)*256 + tid
    int I0 = (int)(__builtin_bit_cast(unsigned, K0) & 0x7FFu);
    int I1 = (int)(__builtin_bit_cast(unsigned, K1) & 0x7FFu);
    int I2 = (int)(__builtin_bit_cast(unsigned, K2) & 0x7FFu);
    float d2m = __builtin_bit_cast(float, __builtin_bit_cast(unsigned, K2) & 0xFFFFF800u);
    float d3m = __builtin_bit_cast(float, __builtin_bit_cast(unsigned, K3) & 0xFFFFF800u);
    // keys shifted by -pp; rescale certification with true magnitude
    bool flag = (d3m - d2m) < 2e-3f * fmaxf(d3m + pp, 0.f) + 1e-5f;
    if (flag) {
      int slot = atomicAdd(flag_count, 1);
      flag_list[slot] = p;
    }
    // exact fp64 weights from chosen indices (original coords, diff form)
    const float* q = sposI + (size_t)b * 3 * NSMP;
    double pxd = (double)fx, pyd = (double)fy, pzd = (double)fz;
    double dd[3]; int II[3] = {I0, I1, I2};
#pragma unroll
    for (int k = 0; k < 3; k++) {
      double dx = pxd - (double)q[3 * II[k]];
      double dy = pyd - (double)q[3 * II[k] + 1];
      double dz = pzd - (double)q[3 * II[k] + 2];
      dd[k] = dx * dx + dy * dy + dz * dz;
    }
    double w0 = 1.0 / (dd[0] + 1e-8);
    double w1 = 1.0 / (dd[1] + 1e-8);
    double w2 = 1.0 / (dd[2] + 1e-8);
    double inv = 1.0 / (w0 + w1 + w2);
    size_t o = (size_t)p * 3;
    idx_out[o + 0] = I0; idx_out[o + 1] = I1; idx_out[o + 2] = I2;
    wgt_out[o + 0] = (float)(w0 * inv);
    wgt_out[o + 1] = (float)(w1 * inv);
    wgt_out[o + 2] = (float)(w2 * inv);
  }
}

// ---------------------------------------------------------------------------
// Exact fp64 fallback, wave-parallel (original coords, difference form).
// ---------------------------------------------------------------------------
__device__ __forceinline__ bool dless(double d, int i, double D, int I) {
  return d < D || (d == D && i < I);
}
__device__ __forceinline__ void dins3(double d, int i,
                                      double& b0, double& b1, double& b2,
                                      int& i0, int& i1, int& i2) {
  if (dless(d, i, b2, i2)) {
    if (dless(d, i, b1, i1)) {
      b2 = b1; i2 = i1;
      if (dless(d, i, b0, i0)) { b1 = b0; i1 = i0; b0 = d; i0 = i; }
      else                     { b1 = d; i1 = i; }
    } else { b2 = d; i2 = i; }
  }
}

__global__ __launch_bounds__(256) void knn_fallback(
    const float* __restrict__ pos, const float* __restrict__ sposI,
    const int* __restrict__ flag_list, const int* __restrict__ flag_count,
    int* __restrict__ idx_out, float* __restrict__ wgt_out) {
  int wave = threadIdx.x >> 6, lane = threadIdx.x & 63;
  int gw = blockIdx.x * 4 + wave;
  int cnt = *flag_count;
  for (int t = gw; t < cnt; t += 1024) {
    int p = flag_list[t];
    int b = p >> 13, n = p & (NPT - 1);
    const float* pb = pos + (size_t)b * 3 * NPT;
    double px = (double)pb[n], py = (double)pb[NPT + n], pz = (double)pb[2 * NPT + n];
    const float* q = sposI + (size_t)b * 3 * NSMP;
    double b0 = 1e300, b1 = 1e300, b2 = 1e300;
    int i0 = 0x7FFFFFFF, i1 = 0x7FFFFFFF, i2 = 0x7FFFFFFF;
    for (int s = lane; s < NSMP; s += 64) {
      double dx = px - (double)q[3 * s];
      double dy = py - (double)q[3 * s + 1];
      double dz = pz - (double)q[3 * s + 2];
      double d = dx * dx + dy * dy + dz * dz;
      dins3(d, s, b0, b1, b2, i0, i1, i2);
    }
#pragma unroll
    for (int m = 1; m < 64; m <<= 1) {
      double o0 = __shfl_xor(b0, m, 64), o1 = __shfl_xor(b1, m, 64), o2 = __shfl_xor(b2, m, 64);
      int    j0 = __shfl_xor(i0, m, 64), j1 = __shfl_xor(i1, m, 64), j2 = __shfl_xor(i2, m, 64);
      dins3(o0, j0, b0, b1, b2, i0, i1, i2);
      dins3(o1, j1, b0, b1, b2, i0, i1, i2);
      dins3(o2, j2, b0, b1, b2, i0, i1, i2);
    }
    if (lane == 0) {
      double w0 = 1.0 / (b0 + 1e-8);
      double w1 = 1.0 / (b1 + 1e-8);
      double w2 = 1.0 / (b2 + 1e-8);
      double inv = 1.0 / (w0 + w1 + w2);
      size_t o = (size_t)p * 3;
      idx_out[o + 0] = i0; idx_out[o + 1] = i1; idx_out[o + 2] = i2;
      wgt_out[o + 0] = (float)(w0 * inv);
      wgt_out[o + 1] = (float)(w1 * inv);
      wgt_out[o + 2] = (float)(w2 * inv);
    }
  }
}

// ---------------------------------------------------------------------------
// Interp gather -> featB columns 128..383 (bf16)
// ---------------------------------------------------------------------------
__global__ __launch_bounds__(256) void interp_kernel(
    const float* __restrict__ sfeatT,  // [B, NSMP, D2C]
    const int* __restrict__ idx,
    const float* __restrict__ wgt,
    unsigned short* __restrict__ featB) {
  int p = blockIdx.x;
  int c = threadIdx.x;
  int b = p >> 13;
  size_t o = (size_t)p * 3;
  int i0 = idx[o], i1 = idx[o + 1], i2 = idx[o + 2];
  float w0 = wgt[o], w1 = wgt[o + 1], w2 = wgt[o + 2];
  const float* base = sfeatT + (size_t)b * NSMP * D2C;
  float v = w0 * base[(size_t)i0 * D2C + c]
          + w1 * base[(size_t)i1 * D2C + c]
          + w2 * base[(size_t)i2 * D2C + c];
  featB[(size_t)p * CIN + D1C + c] = f2bf(v);
}

// ---------------------------------------------------------------------------
// GEMM1, single-wave blocks: Y1 = featB @ W1^T + b1, 128x64 tile/wave.
// grid (NRB, C1/WN) = (512, 4), block 64.
// ---------------------------------------------------------------------------
__global__ __launch_bounds__(64) void gemm1_wave(
    const unsigned short* __restrict__ featB,  // [BN_TOTAL][CIN] bf16
    const unsigned short* __restrict__ W1h,    // [C1][CIN] bf16
    const float* __restrict__ bias,
    unsigned short* __restrict__ Y1,           // [BN_TOTAL][C1] bf16
    float* __restrict__ part_s,                // [C1][NRB]
    float* __restrict__ part_q) {
  __shared__ __align__(16) unsigned short As[WM * WK];  // 8 KB
  __shared__ __align__(16) unsigned short Bs[WN * WK];  // 4 KB
  int lane = threadIdx.x;
  int m16 = lane & 15, quad = lane >> 4;
  int rb = blockIdx.x, cb = blockIdx.y;
  int row0 = rb * WM, col0 = cb * WN;
  int row16 = lane >> 2, col8 = (lane & 3) * 8;

  f32x4 acc[8][4];
#pragma unroll
  for (int j = 0; j < 4; j++) {
    float bj = bias[col0 + j * 16 + m16];
#pragma unroll
    for (int i = 0; i < 8; i++) acc[i][j] = f32x4{bj, bj, bj, bj};
  }

  for (int k0 = 0; k0 < CIN; k0 += WK) {
#pragma unroll
    for (int c = 0; c < 8; c++)
      gld_lds16(&featB[(size_t)(row0 + c * 16 + row16) * CIN + k0 + col8],
                &As[c * 16 * WK]);
#pragma unroll
    for (int c = 0; c < 4; c++)
      gld_lds16(&W1h[(size_t)(col0 + c * 16 + row16) * CIN + k0 + col8],
                &Bs[c * 16 * WK]);
    __syncthreads();  // 1-wave block: local waitcnt, no cross-wave drain

    bf16x8 a[8], bf[4];
#pragma unroll
    for (int i = 0; i < 8; i++)
      a[i] = __builtin_bit_cast(bf16x8, *(const s16x8*)&As[(i * 16 + m16) * WK + quad * 8]);
#pragma unroll
    for (int j = 0; j < 4; j++)
      bf[j] = __builtin_bit_cast(bf16x8, *(const s16x8*)&Bs[(j * 16 + m16) * WK + quad * 8]);
#pragma unroll
    for (int i = 0; i < 8; i++)
#pragma unroll
      for (int j = 0; j < 4; j++)
        acc[i][j] = __builtin_amdgcn_mfma_f32_16x16x32_bf16(a[i], bf[j], acc[i][j], 0, 0, 0);
    __syncthreads();
  }

#pragma unroll
  for (int j = 0; j < 4; j++) {
    int col = col0 + j * 16 + m16;
    float s = 0.f, q = 0.f;
#pragma unroll
    for (int i = 0; i < 8; i++)
#pragma unroll
      for (int r = 0; r < 4; r++) {
        float v = acc[i][j][r];
        Y1[(size_t)(row0 + i * 16 + quad * 4 + r) * C1 + col] = f2bf(v);
        s += v; q = fmaf(v, v, q);
      }
    s += __shfl_xor(s, 16, 64); s += __shfl_xor(s, 32, 64);
    q += __shfl_xor(q, 16, 64); q += __shfl_xor(q, 32, 64);
    if (quad == 0) {
      part_s[(size_t)col * NRB + rb] = s;
      part_q[(size_t)col * NRB + rb] = q;
    }
  }
}

// ---------------------------------------------------------------------------
// GEMM2, single-wave blocks: X2 = relu(bn1(Y1)) fused in A staging (VALU),
// B via global_load_lds. 128x64 tile/wave. grid (NRB, C2/WN) = (512, 2).
// ---------------------------------------------------------------------------
__global__ __launch_bounds__(64) void gemm2_wave(
    const unsigned short* __restrict__ Y1,   // [BN_TOTAL][C1] bf16
    const float* __restrict__ scale1, const float* __restrict__ shift1,
    const unsigned short* __restrict__ W2h,  // [C2][C1] bf16
    const float* __restrict__ bias,
    unsigned short* __restrict__ Y2,         // [BN_TOTAL][C2] bf16
    float* __restrict__ part_s,              // [C2][NRB]
    float* __restrict__ part_q) {
  __shared__ __align__(16) unsigned short As[WM * WK];
  __shared__ __align__(16) unsigned short Bs[WN * WK];
  __shared__ float scs[C1], shs[C1];
  int lane = threadIdx.x;
  int m16 = lane & 15, quad = lane >> 4;
  int rb = blockIdx.x, cb = blockIdx.y;
  int row0 = rb * WM, col0 = cb * WN;
  int row16 = lane >> 2, col8 = (lane & 3) * 8;

  for (int t = lane; t < C1; t += 64) { scs[t] = scale1[t]; shs[t] = shift1[t]; }

  f32x4 acc[8][4];
#pragma unroll
  for (int j = 0; j < 4; j++) {
    float bj = bias[col0 + j * 16 + m16];
#pragma unroll
    for (int i = 0; i < 8; i++) acc[i][j] = f32x4{bj, bj, bj, bj};
  }
  __syncthreads();  // scs/shs visible (single wave: cheap)

  for (int k0 = 0; k0 < C1; k0 += WK) {
#pragma unroll
    for (int c = 0; c < 4; c++)
      gld_lds16(&W2h[(size_t)(col0 + c * 16 + row16) * C1 + k0 + col8],
                &Bs[c * 16 * WK]);
    // A tile: load Y1, apply BN1+ReLU, write LDS
#pragma unroll
    for (int c = 0; c < 8; c++) {
      int row = c * 16 + row16;
      s16x8 v = *(const s16x8*)&Y1[(size_t)(row0 + row) * C1 + k0 + col8];
      unsigned short ov[8];
#pragma unroll
      for (int e = 0; e < 8; e++) {
        float x = bf2f((unsigned short)v[e]);
        float y = fmaxf(fmaf(x, scs[k0 + col8 + e], shs[k0 + col8 + e]), 0.f);
        ov[e] = f2bf(y);
      }
      *(s16x8*)&As[row * WK + col8] = *(const s16x8*)ov;
    }
    __syncthreads();

    bf16x8 a[8], bf[4];
#pragma unroll
    for (int i = 0; i < 8; i++)
      a[i] = __builtin_bit_cast(bf16x8, *(const s16x8*)&As[(i * 16 + m16) * WK + quad * 8]);
#pragma unroll
    for (int j = 0; j < 4; j++)
      bf[j] = __builtin_bit_cast(bf16x8, *(const s16x8*)&Bs[(j * 16 + m16) * WK + quad * 8]);
#pragma unroll
    for (int i = 0; i < 8; i++)
#pragma unroll
      for (int j = 0; j < 4; j++)
        acc[i][j] = __builtin_amdgcn_mfma_f32_16x16x32_bf16(a[i], bf[j], acc[i][j], 0, 0, 0);
    __syncthreads();
  }

#pragma unroll
  for (int j = 0; j < 4; j++) {
    int col = col0 + j * 16 + m16;
    float s = 0.f, q = 0.f;
#pragma unroll
    for (int i = 0; i < 8; i++)
#pragma unroll
      for (int r = 0; r < 4; r++) {
        float v = acc[i][j][r];
        Y2[(size_t)(row0 + i * 16 + quad * 4 + r) * C2 + col] = f2bf(v);
        s += v; q = fmaf(v, v, q);
      }
    s += __shfl_xor(s, 16, 64); s += __shfl_xor(s, 32, 64);
    q += __shfl_xor(q, 16, 64); q += __shfl_xor(q, 32, 64);
    if (quad == 0) {
      part_s[(size_t)col * NRB + rb] = s;
      part_q[(size_t)col * NRB + rb] = q;
    }
  }
}

// ---------------------------------------------------------------------------
// Reduce partials [C][NRB] + compute BN scale/shift. grid = C, block = 256.
// ---------------------------------------------------------------------------
__global__ __launch_bounds__(256) void bn_reduce_coef(
    const float* __restrict__ part_s, const float* __restrict__ part_q, int nrb,
    const float* __restrict__ g, const float* __restrict__ beta,
    float* __restrict__ scale, float* __restrict__ shift) {
  int ch = blockIdx.x;
  int tid = threadIdx.x;
  float s = 0.f, q = 0.f;
  for (int t = tid; t < nrb; t += 256) {
    s += part_s[(size_t)ch * nrb + t];
    q += part_q[(size_t)ch * nrb + t];
  }
#pragma unroll
  for (int m = 1; m < 64; m <<= 1) {
    s += __shfl_xor(s, m, 64);
    q += __shfl_xor(q, m, 64);
  }
  __shared__ float ls[4], lq[4];
  int wave = tid >> 6;
  if ((tid & 63) == 0) { ls[wave] = s; lq[wave] = q; }
  __syncthreads();
  if (tid == 0) {
    s = ls[0] + ls[1] + ls[2] + ls[3];
    q = lq[0] + lq[1] + lq[2] + lq[3];
    const float invBN = 1.0f / (float)BN_TOTAL;
    float mean = s * invBN;
    float var = q * invBN - mean * mean;
    float sc = g[ch] / sqrtf(var + 1e-5f);
    scale[ch] = sc;
    shift[ch] = beta[ch] - mean * sc;
  }
}

// ---------------------------------------------------------------------------
// Final: out[b][c][n] = relu(bn2(Y2)) transposed, fp32 out.
// ---------------------------------------------------------------------------
__global__ void final_kernel(const unsigned short* __restrict__ Y2,
                             const float* __restrict__ scale, const float* __restrict__ shift,
                             float* __restrict__ out) {
  __shared__ float tile[32][33];
  int b = blockIdx.z;
  int n0 = blockIdx.x * 32;
  int c0 = blockIdx.y * 32;
  int tx = threadIdx.x, ty = threadIdx.y;
  float sc = scale[c0 + tx];
  float sh = shift[c0 + tx];
#pragma unroll
  for (int i = 0; i < 32; i += 8) {
    int n = n0 + ty + i;
    float v = bf2f(Y2[((size_t)b * NPT + n) * C2 + c0 + tx]);
    tile[ty + i][tx] = fmaxf(fmaf(v, sc, sh), 0.f);
  }
  __syncthreads();
#pragma unroll
  for (int i = 0; i < 32; i += 8) {
    int c = c0 + ty + i;
    out[((size_t)b * C2 + c) * NPT + n0 + tx] = tile[tx][ty + i];
  }
}

// ---------------------------------------------------------------------------
extern "C" void kernel_launch(void* const* d_in, const int* in_sizes, int n_in,
                              void* d_out, int out_size, void* d_ws, size_t ws_size,
                              hipStream_t stream) {
  (void)in_sizes; (void)n_in; (void)out_size; (void)ws_size;
  const float* pos   = (const float*)d_in[0];
  const float* spos  = (const float*)d_in[1];
  const float* skip  = (const float*)d_in[2];
  const float* sfeat = (const float*)d_in[3];
  const float* W1    = (const float*)d_in[4];
  const float* b1    = (const float*)d_in[5];
  const float* g1    = (const float*)d_in[6];
  const float* beta1 = (const float*)d_in[7];
  const float* W2    = (const float*)d_in[8];
  const float* b2    = (const float*)d_in[9];
  const float* g2    = (const float*)d_in[10];
  const float* beta2 = (const float*)d_in[11];
  float* out = (float*)d_out;

  float* ws = (float*)d_ws;
  size_t off = 0;
  float* sfeatT  = ws + off; off += (size_t)BATCH * NSMP * D2C;
  unsigned short* featB = (unsigned short*)(ws + off); off += (size_t)BN_TOTAL * CIN / 2;
  unsigned short* Y1    = (unsigned short*)(ws + off); off += (size_t)BN_TOTAL * C1 / 2;
  unsigned short* Y2    = (unsigned short*)(ws + off); off += (size_t)BN_TOTAL * C2 / 2;
  unsigned short* W1h   = (unsigned short*)(ws + off); off += (size_t)C1 * CIN / 2;
  unsigned short* W2h   = (unsigned short*)(ws + off); off += (size_t)C2 * C1 / 2;
  int*   knn_idx = (int*)(ws + off); off += (size_t)BN_TOTAL * 3;
  float* knn_w   = ws + off; off += (size_t)BN_TOTAL * 3;
  float* sposI   = ws + off; off += (size_t)BATCH * NSMP * 3;
  float4* qs4    = (float4*)(ws + off); off += (size_t)BATCH * NSMP * 4;
  int* flag_list = (int*)(ws + off); off += (size_t)BN_TOTAL;
  float* part1_s = ws + off; off += (size_t)C1 * NRB;
  float* part1_q = ws + off; off += (size_t)C1 * NRB;
  float* part2_s = ws + off; off += (size_t)C2 * NRB;
  float* part2_q = ws + off; off += (size_t)C2 * NRB;
  float* stats   = ws + off; off += 2048;
  int*   flag_count = (int*)stats;
  float* scale1 = stats + 256, *shift1 = stats + 512;
  float* scale2 = stats + 768, *shift2 = stats + 1024;

  hipMemsetAsync(flag_count, 0, sizeof(int), stream);

  dim3 tb(32, 8);
  transpose_k<<<dim3(NSMP / 32, D2C / 32, BATCH), tb, 0, stream>>>(
      sfeat, sfeatT, D2C, NSMP, (long)D2C * NSMP, (long)NSMP * D2C);
  wprep<<<(C1 * CIN + 255) / 256, 256, 0, stream>>>(W1, W1h, C1 * CIN);
  wprep<<<(C2 * C1 + 255) / 256, 256, 0, stream>>>(W2, W2h, C2 * C1);
  skip_to_featB<<<dim3(NPT / 32, D1C / 32, BATCH), tb, 0, stream>>>(skip, featB);

  pack_spos<<<BATCH * NSMP / 256, 256, 0, stream>>>(spos, sposI, qs4);
  knn_kernel<<<BN_TOTAL / 256, 256, 0, stream>>>(pos, qs4, sposI, knn_idx, knn_w,
                                                 flag_list, flag_count);
  knn_fallback<<<256, 256, 0, stream>>>(pos, sposI, flag_list, flag_count,
                                        knn_idx, knn_w);
  interp_kernel<<<BN_TOTAL, 256, 0, stream>>>(sfeatT, knn_idx, knn_w, featB);

  gemm1_wave<<<dim3(NRB, C1 / WN), 64, 0, stream>>>(
      featB, W1h, b1, Y1, part1_s, part1_q);
  bn_reduce_coef<<<C1, 256, 0, stream>>>(part1_s, part1_q, NRB, g1, beta1, scale1, shift1);

  gemm2_wave<<<dim3(NRB, C2 / WN), 64, 0, stream>>>(
      Y1, scale1, shift1, W2h, b2, Y2, part2_s, part2_q);
  bn_reduce_coef<<<C2, 256, 0, stream>>>(part2_s, part2_q, NRB, g2, beta2, scale2, shift2);

  final_kernel<<<dim3(NPT / 32, C2 / 32, BATCH), tb, 0, stream>>>(Y2, scale2, shift2, out);
}